// Round 1
// baseline (307.263 us; speedup 1.0000x reference)
//
#include <hip/hip_runtime.h>
#include <stdint.h>

#define BB   4
#define NQ   8192
#define NS   4096
#define FDIM 256
#define KNN  8
#define G    8             // lanes per query
#define QPB  32            // queries per block (256 threads / G)
#define SCAN (NS / G)      // 512 sensors scanned per lane

typedef unsigned long long u64;

__device__ __forceinline__ void cswap(u64& a, u64& b) {
    u64 x = a, y = b;
    bool sw = y < x;
    a = sw ? y : x;
    b = sw ? x : y;
}

__global__ __launch_bounds__(256) void idw_kernel(
    const float* __restrict__ qc,   // (B*NQ, 3)
    const float* __restrict__ sc,   // (NS, 3)
    const float* __restrict__ sf,   // (B, NS, FDIM)
    float* __restrict__ out)        // (B*NQ, FDIM)
{
    __shared__ float s_coord[NS * 3];            // 48 KB
    __shared__ int   s_idx[QPB][KNN];
    __shared__ float s_w[QPB][KNN];

    const int tid = threadIdx.x;
    const int q0  = blockIdx.x * QPB;
    const int b   = q0 / NQ;                     // uniform per block (256 blocks per b)

    // ---- stage sensor coords to LDS (coalesced float4) ----
    {
        const float4* src = (const float4*)sc;
        float4* dst = (float4*)s_coord;
        #pragma unroll
        for (int j = 0; j < (NS * 3 / 4) / 256; ++j)   // 12 iters
            dst[tid + 256 * j] = src[tid + 256 * j];
    }
    __syncthreads();

    const int g = tid >> 3;        // query group in block: 0..31
    const int l = tid & 7;         // lane within group: 0..7

    const float* qp = qc + (size_t)(q0 + g) * 3;
    const float qx = qp[0], qy = qp[1], qz = qp[2];
    const float q2 = qx * qx + qy * qy + qz * qz;

    // ---- phase A: per-lane top-8 over a strided sensor subset ----
    u64 k[KNN];
    #pragma unroll
    for (int j = 0; j < KNN; ++j) k[j] = ~0ull;

    int s = l;
    for (int t = 0; t < SCAN; ++t, s += G) {
        const float sx = s_coord[3 * s + 0];
        const float sy = s_coord[3 * s + 1];
        const float sz = s_coord[3 * s + 2];
        const float dot = qx * sx + qy * sy + qz * sz;
        const float s2  = sx * sx + sy * sy + sz * sz;
        const float d2  = fmaxf(q2 + s2 - 2.0f * dot, 0.0f);
        const float d   = sqrtf(d2);
        const u64 key = ((u64)__float_as_uint(d) << 32) | (unsigned)s;
        if (key < k[KNN - 1]) {                // gate: beats current 8th-best?
            k[KNN - 1] = key;
            #pragma unroll
            for (int j = KNN - 1; j > 0; --j) cswap(k[j - 1], k[j]);
        }
    }

    // ---- merge 8 lanes x 8 sorted keys -> global top-8 (8 tournament rounds) ----
    u64 sel = 0;
    #pragma unroll
    for (int r = 0; r < KNN; ++r) {
        u64 v = k[0];
        #pragma unroll
        for (int m = 1; m <= 4; m <<= 1) {
            u64 o = __shfl_xor(v, m, 64);      // stays within the 8-lane group
            v = o < v ? o : v;
        }
        if (k[0] == v) {                       // exactly one lane pops (keys unique)
            #pragma unroll
            for (int j = 0; j < KNN - 1; ++j) k[j] = k[j + 1];
            k[KNN - 1] = ~0ull;
        }
        if (l == r) sel = v;                   // lane r keeps round-r winner
    }

    // ---- weights: w = 1/(d+eps), normalized over the 8 lanes of the group ----
    const float dsel = __uint_as_float((unsigned)(sel >> 32));
    const int   idx  = (int)(unsigned)(sel & 0xFFFFFFFFu);
    float w  = 1.0f / (dsel + 1e-8f);
    float ws = w;
    #pragma unroll
    for (int m = 1; m <= 4; m <<= 1) ws += __shfl_xor(ws, m, 64);
    const float wn = w / ws;
    s_idx[g][l] = idx;
    s_w[g][l]   = wn;

    __syncthreads();

    // ---- phase B: one wave per query, 64 lanes x float4 = 256 features ----
    const int wave = tid >> 6;
    const int lane = tid & 63;
    const float* fb = sf + (size_t)b * NS * FDIM;
    #pragma unroll 1
    for (int j = 0; j < QPB / 4; ++j) {        // 8 queries per wave
        const int ql = wave * (QPB / 4) + j;
        float4 acc = {0.f, 0.f, 0.f, 0.f};
        #pragma unroll
        for (int kk = 0; kk < KNN; ++kk) {
            const int   sid = s_idx[ql][kk];   // LDS broadcast
            const float wk  = s_w[ql][kk];
            const float4 v = ((const float4*)(fb + (size_t)sid * FDIM))[lane];
            acc.x += wk * v.x; acc.y += wk * v.y;
            acc.z += wk * v.z; acc.w += wk * v.w;
        }
        ((float4*)(out + (size_t)(q0 + ql) * FDIM))[lane] = acc;
    }
}

extern "C" void kernel_launch(void* const* d_in, const int* in_sizes, int n_in,
                              void* d_out, int out_size, void* d_ws, size_t ws_size,
                              hipStream_t stream) {
    const float* qc = (const float*)d_in[0];   // query_coords  (4,8192,3)
    const float* sc = (const float*)d_in[1];   // sensor_coords (4096,3)
    const float* sf = (const float*)d_in[2];   // sensor_features (4,4096,256)
    float* out = (float*)d_out;                // (4,8192,256)

    dim3 grid((BB * NQ) / QPB);                // 1024 blocks
    dim3 block(256);
    idw_kernel<<<grid, block, 0, stream>>>(qc, sc, sf, out);
}

// Round 2
// 170.505 us; speedup vs baseline: 1.8021x; 1.8021x over previous
//
#include <hip/hip_runtime.h>
#include <stdint.h>

#define BB   4
#define NQ   8192
#define NS   4096
#define FDIM 256
#define KNN  8
#define G    8              // lanes per query
#define NT   512            // threads per block
#define QPB  (NT / G)       // 64 queries per block
#define SCAN (NS / G)       // 512 sensors per lane

typedef unsigned long long u64;

__global__ __launch_bounds__(NT, 4) void idw_kernel(
    const float* __restrict__ qc,   // (B*NQ, 3)
    const float* __restrict__ sc,   // (NS, 3)
    const float* __restrict__ sf,   // (B, NS, FDIM)
    float* __restrict__ out)        // (B*NQ, FDIM)
{
    __shared__ float4 s_f4[NS];            // 64 KB: (x, y, z, |s|^2)
    // After phase A (post-barrier), first 4 KB is reused for the handoff:
    int*   s_idx = (int*)s_f4;             // [QPB*KNN] = 2 KB
    float* s_w   = (float*)s_f4 + QPB*KNN; // [QPB*KNN] = 2 KB

    const int tid = threadIdx.x;
    const int q0  = blockIdx.x * QPB;
    const int b   = q0 / NQ;               // uniform per block (128 blocks per batch)

    // ---- stage sensor coords + precomputed |s|^2 ----
    for (int s = tid; s < NS; s += NT) {
        const float sx = sc[3*s+0], sy = sc[3*s+1], sz = sc[3*s+2];
        s_f4[s] = make_float4(sx, sy, sz, sx*sx + sy*sy + sz*sz);
    }
    __syncthreads();

    const int g = tid >> 3;                // query within block: 0..63
    const int l = tid & 7;                 // lane within query group: 0..7

    const float* qp = qc + (size_t)(q0 + g) * 3;
    const float qx = qp[0], qy = qp[1], qz = qp[2];
    const float q2 = qx*qx + qy*qy + qz*qz;

    // ---- phase A: branchless sorted top-8 of d^2 over a strided subset ----
    float kd[KNN]; int ki[KNN];
    #pragma unroll
    for (int j = 0; j < KNN; ++j) { kd[j] = 3.4e38f; ki[j] = 0; }

    #pragma unroll 2
    for (int t = 0; t < SCAN; ++t) {
        const int s = t * G + l;
        const float4 v = s_f4[s];
        const float dot = qx*v.x + qy*v.y + qz*v.z;
        const float x   = fmaf(-2.0f, dot, q2 + v.w);   // d^2 (can be ~-1e-7)

        bool f[KNN];
        #pragma unroll
        for (int j = 0; j < KNN; ++j) f[j] = x < kd[j]; // monotone 0..0,1..1
        // shift-insert, in place, descending (kd[j-1] still old when used)
        #pragma unroll
        for (int j = KNN - 1; j >= 1; --j) {
            kd[j] = f[j-1] ? kd[j-1] : (f[j] ? x : kd[j]);
            ki[j] = f[j-1] ? ki[j-1] : (f[j] ? s : ki[j]);
        }
        kd[0] = f[0] ? x : kd[0];
        ki[0] = f[0] ? s : ki[0];
    }

    // ---- pack (clamped d^2, idx) -> u64 keys; clamp preserves sort order ----
    u64 k[KNN];
    #pragma unroll
    for (int j = 0; j < KNN; ++j) {
        const float dc = fmaxf(kd[j], 0.0f);
        k[j] = ((u64)__float_as_uint(dc) << 32) | (unsigned)ki[j];
    }

    // ---- merge 8 lanes x 8 sorted -> global top-8 (8 tournament rounds) ----
    u64 sel = 0;
    #pragma unroll
    for (int r = 0; r < KNN; ++r) {
        u64 v = k[0];
        #pragma unroll
        for (int m = 1; m <= 4; m <<= 1) {
            const u64 o = __shfl_xor(v, m, 64);   // stays within 8-lane group
            v = o < v ? o : v;
        }
        if (k[0] == v) {                          // exactly one lane pops (idx unique)
            #pragma unroll
            for (int j = 0; j < KNN - 1; ++j) k[j] = k[j+1];
            k[KNN-1] = ~0ull;
        }
        if (l == r) sel = v;
    }

    // ---- weights ----
    const float dsel = sqrtf(__uint_as_float((unsigned)(sel >> 32)));
    const int   idx  = (int)(unsigned)(sel & 0xFFFFFFFFu);
    float w  = 1.0f / (dsel + 1e-8f);
    float ws = w;
    #pragma unroll
    for (int m = 1; m <= 4; m <<= 1) ws += __shfl_xor(ws, m, 64);
    const float wn = w / ws;

    __syncthreads();                 // everyone done reading s_f4 coords
    s_idx[g * KNN + l] = idx;
    s_w  [g * KNN + l] = wn;
    __syncthreads();

    // ---- phase B: one wave per query, 64 lanes x float4 = 256 features ----
    const int wave = tid >> 6;       // 0..7
    const int lane = tid & 63;
    const float* fb = sf + (size_t)b * NS * FDIM;
    #pragma unroll 1
    for (int j = 0; j < QPB / 8; ++j) {          // 8 queries per wave
        const int ql = wave * (QPB / 8) + j;
        float4 acc = {0.f, 0.f, 0.f, 0.f};
        #pragma unroll
        for (int kk = 0; kk < KNN; ++kk) {
            const int   sid = s_idx[ql * KNN + kk];   // LDS broadcast
            const float wk  = s_w  [ql * KNN + kk];
            const float4 v = ((const float4*)(fb + (size_t)sid * FDIM))[lane];
            acc.x += wk * v.x; acc.y += wk * v.y;
            acc.z += wk * v.z; acc.w += wk * v.w;
        }
        ((float4*)(out + (size_t)(q0 + ql) * FDIM))[lane] = acc;
    }
}

extern "C" void kernel_launch(void* const* d_in, const int* in_sizes, int n_in,
                              void* d_out, int out_size, void* d_ws, size_t ws_size,
                              hipStream_t stream) {
    const float* qc = (const float*)d_in[0];   // query_coords  (4,8192,3)
    const float* sc = (const float*)d_in[1];   // sensor_coords (4096,3)
    const float* sf = (const float*)d_in[2];   // sensor_features (4,4096,256)
    float* out = (float*)d_out;                // (4,8192,256)

    dim3 grid((BB * NQ) / QPB);                // 512 blocks
    dim3 block(NT);
    idw_kernel<<<grid, block, 0, stream>>>(qc, sc, sf, out);
}

// Round 3
// 99.902 us; speedup vs baseline: 3.0756x; 1.7067x over previous
//
#include <hip/hip_runtime.h>
#include <stdint.h>

#define BB   4
#define NQ   8192
#define NS   4096
#define FDIM 256
#define KNN  8
#define G    8              // lanes per query
#define NT   512            // threads per block
#define QPB  (NT / G)       // 64 queries per block
#define SCAN (NS / G)       // 512 sensors per lane
#define CAP  16             // collection capacity per query (ties spill)

typedef unsigned long long u64;

// Bit-exact distance^2: fixed rounding ops, no contraction freedom, so pass A
// and pass C compute identical f32 values (threshold membership is exact).
#define DIST2(v) __fmaf_rn(-2.0f, \
    __fmaf_rn(qx, (v).x, __fmaf_rn(qy, (v).y, __fmul_rn(qz, (v).z))), \
    __fadd_rn(q2, (v).w))

__device__ __forceinline__ float med3(float a, float b, float c) {
    return __builtin_amdgcn_fmed3f(a, b, c);
}

__global__ __launch_bounds__(NT, 4) void idw_kernel(
    const float* __restrict__ qc,   // (B*NQ, 3)
    const float* __restrict__ sc,   // (NS, 3)
    const float* __restrict__ sf,   // (B, NS, FDIM)
    float* __restrict__ out)        // (B*NQ, FDIM)
{
    __shared__ float4 s_f4[NS];            // 64 KB: (x, y, z, |s|^2)
    __shared__ u64    s_items[QPB * CAP];  // 8 KB
    __shared__ int    s_cnt[QPB];
    __shared__ int    s_idx[QPB * KNN];
    __shared__ float  s_w[QPB * KNN];

    const int tid = threadIdx.x;

    // XCD-aware swizzle: batch b -> XCD pair {2b, 2b+1} (assumes round-robin
    // dispatch). Bijective over 512 blocks; affects locality only.
    const int p   = blockIdx.x;
    const int b   = (p >> 1) & 3;
    const int sub = ((p >> 3) << 1) | (p & 1);
    const int q0  = b * NQ + sub * QPB;

    // ---- stage coords + precomputed |s|^2; zero counters ----
    for (int s = tid; s < NS; s += NT) {
        const float sx = sc[3*s+0], sy = sc[3*s+1], sz = sc[3*s+2];
        s_f4[s] = make_float4(sx, sy, sz,
                              __fmaf_rn(sx, sx, __fmaf_rn(sy, sy, __fmul_rn(sz, sz))));
    }
    if (tid < QPB) s_cnt[tid] = 0;
    __syncthreads();

    const int g = tid >> 3;        // query within block: 0..63
    const int l = tid & 7;         // lane within query group: 0..7

    const float* qp = qc + (size_t)(q0 + g) * 3;
    const float qx = qp[0], qy = qp[1], qz = qp[2];
    const float q2 = __fmaf_rn(qx, qx, __fmaf_rn(qy, qy, __fmul_rn(qz, qz)));

    // ---- pass A: value-only sorted top-8 of d^2 via med3-insert ----
    float kd[KNN];
    #pragma unroll
    for (int j = 0; j < KNN; ++j) kd[j] = 3.4e38f;

    #pragma unroll 4
    for (int t = 0; t < SCAN; ++t) {
        const float4 v = s_f4[t * G + l];
        const float  x = DIST2(v);
        const float nk0 = fminf(kd[0], x);
        #pragma unroll
        for (int j = KNN - 1; j >= 1; --j) kd[j] = med3(kd[j-1], kd[j], x);
        kd[0] = nk0;
    }

    // ---- merge: 8-round pop-tournament -> global 8th-smallest (threshold) ----
    // Cross-lane equal values over-pop, which can only RAISE thr; the spill is
    // caught by the cnt>8 tie path below. Never under-pops.
    float thr = 3.4e38f;
    #pragma unroll
    for (int r = 0; r < KNN; ++r) {
        float m = kd[0];
        m = fminf(m, __shfl_xor(m, 1, 64));
        m = fminf(m, __shfl_xor(m, 2, 64));
        m = fminf(m, __shfl_xor(m, 4, 64));
        const bool pop = (kd[0] == m);
        #pragma unroll
        for (int j = 0; j < KNN - 1; ++j) kd[j] = pop ? kd[j+1] : kd[j];
        kd[KNN-1] = pop ? 3.4e38f : kd[KNN-1];
        thr = m;
    }

    // ---- pass C: membership re-scan, collect (d^2, idx) of hits ----
    #pragma unroll 4
    for (int t = 0; t < SCAN; ++t) {
        const int s = t * G + l;
        const float4 v = s_f4[s];
        const float  x = DIST2(v);
        if (x <= thr) {
            const u64 key = ((u64)__float_as_uint(x) << 32) | (unsigned)s;
            const int pos = atomicAdd(&s_cnt[g], 1);
            if (pos < CAP) s_items[g * CAP + pos] = key;
        }
    }
    __syncthreads();

    // ---- rare tie fix: keep 8 smallest (d^2, idx) keys (lower idx wins) ----
    if (l == 0) {
        int cnt = s_cnt[g];
        if (cnt > KNN) {
            cnt = cnt < CAP ? cnt : CAP;
            u64 best[KNN];
            #pragma unroll
            for (int j = 0; j < KNN; ++j) best[j] = ~0ull;
            for (int i = 0; i < cnt; ++i) {
                const u64 key = s_items[g * CAP + i];
                bool f[KNN];
                #pragma unroll
                for (int j = 0; j < KNN; ++j) f[j] = key < best[j];
                #pragma unroll
                for (int j = KNN - 1; j >= 1; --j)
                    best[j] = f[j-1] ? best[j-1] : (f[j] ? key : best[j]);
                best[0] = f[0] ? key : best[0];
            }
            #pragma unroll
            for (int j = 0; j < KNN; ++j) s_items[g * CAP + j] = best[j];
        }
    }
    __syncthreads();

    // ---- weights (order-independent: output is sum w_k * f_k) ----
    {
        const u64 key = s_items[g * CAP + l];
        const float d2v = __uint_as_float((unsigned)(key >> 32));
        const int   idx = (int)(unsigned)(key & 0xFFFFFFFFu);
        const float d   = sqrtf(fmaxf(d2v, 0.0f));
        const float w   = 1.0f / (d + 1e-8f);
        float ws = w;
        ws += __shfl_xor(ws, 1, 64);
        ws += __shfl_xor(ws, 2, 64);
        ws += __shfl_xor(ws, 4, 64);
        s_idx[g * KNN + l] = idx;
        s_w  [g * KNN + l] = w / ws;
    }
    __syncthreads();

    // ---- phase B: one wave per query, 64 lanes x float4 = 256 features ----
    const int wave = tid >> 6;       // 0..7
    const int lane = tid & 63;
    const float* fb = sf + (size_t)b * NS * FDIM;
    #pragma unroll 1
    for (int j = 0; j < QPB / 8; ++j) {          // 8 queries per wave
        const int ql = wave * (QPB / 8) + j;
        float4 acc = {0.f, 0.f, 0.f, 0.f};
        #pragma unroll
        for (int kk = 0; kk < KNN; ++kk) {
            const int   sid = s_idx[ql * KNN + kk];   // LDS broadcast
            const float wk  = s_w  [ql * KNN + kk];
            const float4 v = ((const float4*)(fb + (size_t)sid * FDIM))[lane];
            acc.x += wk * v.x; acc.y += wk * v.y;
            acc.z += wk * v.z; acc.w += wk * v.w;
        }
        ((float4*)(out + (size_t)(q0 + ql) * FDIM))[lane] = acc;
    }
}

extern "C" void kernel_launch(void* const* d_in, const int* in_sizes, int n_in,
                              void* d_out, int out_size, void* d_ws, size_t ws_size,
                              hipStream_t stream) {
    const float* qc = (const float*)d_in[0];   // query_coords  (4,8192,3)
    const float* sc = (const float*)d_in[1];   // sensor_coords (4096,3)
    const float* sf = (const float*)d_in[2];   // sensor_features (4,4096,256)
    float* out = (float*)d_out;                // (4,8192,256)

    dim3 grid((BB * NQ) / QPB);                // 512 blocks
    dim3 block(NT);
    idw_kernel<<<grid, block, 0, stream>>>(qc, sc, sf, out);
}

// Round 4
// 93.468 us; speedup vs baseline: 3.2874x; 1.0688x over previous
//
#include <hip/hip_runtime.h>
#include <stdint.h>

#define BB   4
#define NQ   8192
#define NS   4096
#define FDIM 256
#define KNN  8
#define G    16             // lanes per query
#define NT   512            // threads per block
#define QPB  (NT / G)       // 32 queries per block
#define SCAN (NS / G)       // 256 sensors per lane
#define CAP  16             // collection capacity per query (ties spill)

typedef unsigned long long u64;

// Selection key x' = s^2 - 2 q.s  (d^2 minus the per-query constant q^2).
// Fixed rounding ops -> bit-identical between pass A and pass C.
#define KEYX(m) __fmaf_rn(qx, (m).x, __fmaf_rn(qy, (m).y, __fmaf_rn(qz, (m).z, (m).w)))

__device__ __forceinline__ float med3(float a, float b, float c) {
    return __builtin_amdgcn_fmed3f(a, b, c);
}

__global__ __launch_bounds__(NT, 4) void idw_kernel(
    const float* __restrict__ qc,   // (B*NQ, 3)
    const float* __restrict__ sc,   // (NS, 3)
    const float* __restrict__ sf,   // (B, NS, FDIM)
    float* __restrict__ out)        // (B*NQ, FDIM)
{
    __shared__ float4 s_m[NS];             // 64 KB: (-2x, -2y, -2z, |s|^2)
    __shared__ u64    s_items[QPB * CAP];  // 4 KB
    __shared__ int    s_cnt[QPB];
    __shared__ int    s_idx[QPB * KNN];
    __shared__ float  s_w[QPB * KNN];

    const int tid = threadIdx.x;

    // XCD-aware swizzle: batch b -> XCD pair {2b, 2b+1} (round-robin dispatch
    // assumption; bijective over 1024 blocks; locality-only).
    const int p   = blockIdx.x;
    const int b   = (p >> 1) & 3;
    const int sub = ((p >> 3) << 1) | (p & 1);
    const int q0  = b * NQ + sub * QPB;

    // ---- stage (-2x,-2y,-2z,s^2); zero counters ----
    for (int s = tid; s < NS; s += NT) {
        const float sx = sc[3*s+0], sy = sc[3*s+1], sz = sc[3*s+2];
        const float s2 = __fmaf_rn(sx, sx, __fmaf_rn(sy, sy, __fmul_rn(sz, sz)));
        s_m[s] = make_float4(-2.0f*sx, -2.0f*sy, -2.0f*sz, s2);
    }
    if (tid < QPB) s_cnt[tid] = 0;
    __syncthreads();

    const int g = tid >> 4;        // query within block: 0..31
    const int l = tid & 15;        // lane within query group: 0..15

    const float* qp = qc + (size_t)(q0 + g) * 3;
    const float qx = qp[0], qy = qp[1], qz = qp[2];
    const float q2 = __fmaf_rn(qx, qx, __fmaf_rn(qy, qy, __fmul_rn(qz, qz)));

    // ---- pass A: value-only sorted top-8 of x' via med3-insert ----
    float kd[KNN];
    #pragma unroll
    for (int j = 0; j < KNN; ++j) kd[j] = 3.4e38f;

    #pragma unroll 4
    for (int t = 0; t < SCAN; ++t) {
        const float x = KEYX(s_m[t * G + l]);
        const float nk0 = fminf(kd[0], x);
        #pragma unroll
        for (int j = KNN - 1; j >= 1; --j) kd[j] = med3(kd[j-1], kd[j], x);
        kd[0] = nk0;
    }

    // ---- merge: 8-round pop-tournament over 16 lanes -> 8th-smallest ----
    // Equal values across lanes over-pop -> thr only RAISED; spill caught by
    // the cnt>8 tie path. Never under-pops.
    float thr = 3.4e38f;
    #pragma unroll
    for (int r = 0; r < KNN; ++r) {
        float m = kd[0];
        m = fminf(m, __shfl_xor(m, 1, 64));
        m = fminf(m, __shfl_xor(m, 2, 64));
        m = fminf(m, __shfl_xor(m, 4, 64));
        m = fminf(m, __shfl_xor(m, 8, 64));
        const bool pop = (kd[0] == m);
        #pragma unroll
        for (int j = 0; j < KNN - 1; ++j) kd[j] = pop ? kd[j+1] : kd[j];
        kd[KNN-1] = pop ? 3.4e38f : kd[KNN-1];
        thr = m;
    }

    // ---- pass C: membership re-scan; collect (d^2, idx) of hits ----
    #pragma unroll 4
    for (int t = 0; t < SCAN; ++t) {
        const int s = t * G + l;
        const float x = KEYX(s_m[s]);
        if (x <= thr) {
            const float dc = fmaxf(__fadd_rn(x, q2), 0.0f);   // d^2, monotone in x
            const u64 key = ((u64)__float_as_uint(dc) << 32) | (unsigned)s;
            const int pos = atomicAdd(&s_cnt[g], 1);
            if (pos < CAP) s_items[g * CAP + pos] = key;
        }
    }
    __syncthreads();

    // ---- rare tie fix: keep 8 smallest (d^2, idx) keys (lower idx wins) ----
    if (l == 0) {
        int cnt = s_cnt[g];
        if (cnt > KNN) {
            cnt = cnt < CAP ? cnt : CAP;
            u64 best[KNN];
            #pragma unroll
            for (int j = 0; j < KNN; ++j) best[j] = ~0ull;
            for (int i = 0; i < cnt; ++i) {
                const u64 key = s_items[g * CAP + i];
                bool f[KNN];
                #pragma unroll
                for (int j = 0; j < KNN; ++j) f[j] = key < best[j];
                #pragma unroll
                for (int j = KNN - 1; j >= 1; --j)
                    best[j] = f[j-1] ? best[j-1] : (f[j] ? key : best[j]);
                best[0] = f[0] ? key : best[0];
            }
            #pragma unroll
            for (int j = 0; j < KNN; ++j) s_items[g * CAP + j] = best[j];
        }
    }
    __syncthreads();

    // ---- weights (order-independent: output is sum w_k * f_k) ----
    if (l < KNN) {
        const u64 key = s_items[g * CAP + l];
        const float d2v = __uint_as_float((unsigned)(key >> 32));
        const int   idx = (int)(unsigned)(key & 0xFFFFFFFFu);
        const float d   = sqrtf(d2v);
        const float w   = 1.0f / (d + 1e-8f);
        float ws = w;
        ws += __shfl_xor(ws, 1, 64);
        ws += __shfl_xor(ws, 2, 64);
        ws += __shfl_xor(ws, 4, 64);
        s_idx[g * KNN + l] = idx;
        s_w  [g * KNN + l] = w / ws;
    }
    __syncthreads();

    // ---- phase B: one wave per query, 64 lanes x float4 = 256 features ----
    const int wave = tid >> 6;       // 0..7
    const int lane = tid & 63;
    const float* fb = sf + (size_t)b * NS * FDIM;
    #pragma unroll 1
    for (int j = 0; j < QPB / 8; ++j) {          // 4 queries per wave
        const int ql = wave * (QPB / 8) + j;
        float4 acc = {0.f, 0.f, 0.f, 0.f};
        #pragma unroll
        for (int kk = 0; kk < KNN; ++kk) {
            const int   sid = s_idx[ql * KNN + kk];   // LDS broadcast
            const float wk  = s_w  [ql * KNN + kk];
            const float4 v = ((const float4*)(fb + (size_t)sid * FDIM))[lane];
            acc.x += wk * v.x; acc.y += wk * v.y;
            acc.z += wk * v.z; acc.w += wk * v.w;
        }
        ((float4*)(out + (size_t)(q0 + ql) * FDIM))[lane] = acc;
    }
}

extern "C" void kernel_launch(void* const* d_in, const int* in_sizes, int n_in,
                              void* d_out, int out_size, void* d_ws, size_t ws_size,
                              hipStream_t stream) {
    const float* qc = (const float*)d_in[0];   // query_coords  (4,8192,3)
    const float* sc = (const float*)d_in[1];   // sensor_coords (4096,3)
    const float* sf = (const float*)d_in[2];   // sensor_features (4,4096,256)
    float* out = (float*)d_out;                // (4,8192,256)

    dim3 grid((BB * NQ) / QPB);                // 1024 blocks
    dim3 block(NT);
    idw_kernel<<<grid, block, 0, stream>>>(qc, sc, sf, out);
}